// Round 1
// baseline (10745.885 us; speedup 1.0000x reference)
//
#include <hip/hip_runtime.h>
#include <stdint.h>

#define SLEN 4096
#define EDIM 256
#define HD 256
#define G4 1024   // 4*HD
#define KT 20
#define START_ID 18
#define STOP_ID 19

// weight split for k_lstm: 32 K-chunks of 4 dwords (8 fp16) each.
// chunks 0..22 (92 dwords) live in VGPRs; chunks 23..31 (36 dwords) live in LDS.
#define NVC 23          // VGPR chunks
#define NLC 9           // LDS chunks
#define LSTM_LDS_BYTES (1024 + 1024 * NLC * 16)   // h dbuf (2*512B) + tail weights

typedef _Float16 half_t;
typedef _Float16 half2_t __attribute__((ext_vector_type(2)));

__device__ __forceinline__ float dot2(uint32_t a, uint32_t b, float acc) {
#if __has_builtin(__builtin_amdgcn_fdot2)
    return __builtin_amdgcn_fdot2(__builtin_bit_cast(half2_t, a),
                                  __builtin_bit_cast(half2_t, b), acc, false);
#else
    half2_t av = __builtin_bit_cast(half2_t, a);
    half2_t bv = __builtin_bit_cast(half2_t, b);
    acc += (float)av.x * (float)bv.x;
    acc += (float)av.y * (float)bv.y;
    return acc;
#endif
}

__device__ __forceinline__ float fsig(float x) { return 1.f / (1.f + __expf(-x)); }
__device__ __forceinline__ float ftanh(float x) { return 1.f - 2.f / (__expf(2.f * x) + 1.f); }

// old (1024-thread) gate-row mapping used by pack/zx kernels:
//   T = old thread id: w = T>>6, l = T&63, j = 16*w + (l&15), g = (l>>4)&3, row o = g*256 + j
// new k_lstm uses 512 threads; thread t handles old rows o(T=t) and o(T=t+512),
// i.e. hidden units j = 16*(t>>6)+(t&15) (0..127) and j+128, gate g = (t>>4)&3.

// ---------------- prep: transpose w_ih into [d][e][o] ----------------
__global__ __launch_bounds__(256) void k_transpose_ih(const float* __restrict__ wf,
                                                      const float* __restrict__ wb,
                                                      float* __restrict__ wT) {
    __shared__ float tile[32][33];
    int d = blockIdx.z;
    const float* w = d ? wb : wf;
    int ob = blockIdx.x * 32;  // over 1024 rows
    int eb = blockIdx.y * 32;  // over 256 cols
    int tx = threadIdx.x & 31, ty = threadIdx.x >> 5;
#pragma unroll
    for (int r = 0; r < 32; r += 8)
        tile[ty + r][tx] = w[(long)(ob + ty + r) * EDIM + eb + tx];
    __syncthreads();
    float* dst = wT + (long)d * EDIM * G4;
#pragma unroll
    for (int r = 0; r < 32; r += 8)
        dst[(long)(eb + ty + r) * G4 + ob + tx] = tile[tx][ty + r];
}

// ---------------- prep: pack w_hh to fp16 in (old) lstm thread order ----------------
__global__ __launch_bounds__(1024) void k_pack_hh(const float* __restrict__ whf,
                                                  const float* __restrict__ whb,
                                                  uint32_t* __restrict__ wpack,
                                                  uint32_t* __restrict__ wtail) {
    int d = blockIdx.y;
    const float* W = d ? whb : whf;
    int t = threadIdx.x;
    int wv = t >> 6, l = t & 63;
    int j = (wv << 4) | (l & 15);
    int g = (l >> 4) & 3;
    int o = g * 256 + j;
    int bx = blockIdx.x;  // 0..91 -> wpack dwords, 92..100 -> wtail chunks
    if (bx < 92) {
        int k = bx * 2;
        half2_t p = {(half_t)W[(long)o * HD + k], (half_t)W[(long)o * HD + k + 1]};
        wpack[(d * 92 + bx) * 1024 + t] = __builtin_bit_cast(uint32_t, p);
    } else {
        int cb = bx - 92;
        uint32_t q[4];
#pragma unroll
        for (int qq = 0; qq < 4; qq++) {
            int k = 2 * (92 + cb * 4 + qq);
            half2_t p = {(half_t)W[(long)o * HD + k], (half_t)W[(long)o * HD + k + 1]};
            q[qq] = __builtin_bit_cast(uint32_t, p);
        }
        uint4* dst = (uint4*)wtail;
        dst[(d * NLC + cb) * 1024 + t] = make_uint4(q[0], q[1], q[2], q[3]);
    }
}

// ---------------- input projections: zxp[d][s][T] = (x_s @ w_ih^T + b)[o(T)] ----------------
__global__ __launch_bounds__(256) void k_zx(const int* __restrict__ sentence,
                                            const float* __restrict__ embed,
                                            const float* __restrict__ wT,
                                            const float* __restrict__ bf,
                                            const float* __restrict__ bb,
                                            float* __restrict__ zxp) {
    int d = blockIdx.y;
    int s0 = blockIdx.x * 16;
    const float* bias = d ? bb : bf;
    __shared__ float xbuf[16][EDIM];
    int tid = threadIdx.x;
    for (int r = 0; r < 16; r++) {
        int row = sentence[s0 + r];
        xbuf[r][tid] = embed[(long)row * EDIM + tid];
    }
    __syncthreads();
    const float* wTd = wT + (long)d * EDIM * G4;
    for (int og = 0; og < 4; og++) {
        float acc[16];
#pragma unroll
        for (int r = 0; r < 16; r++) acc[r] = 0.f;
        int o = og * 256 + tid;
        for (int e = 0; e < EDIM; e += 4) {
            float w0 = wTd[(long)(e + 0) * G4 + o];
            float w1 = wTd[(long)(e + 1) * G4 + o];
            float w2 = wTd[(long)(e + 2) * G4 + o];
            float w3 = wTd[(long)(e + 3) * G4 + o];
#pragma unroll
            for (int r = 0; r < 16; r++) {
                float4 x4 = *(const float4*)&xbuf[r][e];
                acc[r] += w0 * x4.x + w1 * x4.y + w2 * x4.z + w3 * x4.w;
            }
        }
        float bv = bias[o];
        int tB = ((tid >> 4) << 6) | (og << 4) | (tid & 15);
#pragma unroll
        for (int r = 0; r < 16; r++)
            zxp[(long)(d * SLEN + s0 + r) * G4 + tB] = acc[r] + bv;
    }
}

// ---------------- the serial BiLSTM: 2 blocks (one per direction) ----------------
// 512 threads, 2 gate-rows per thread. __launch_bounds__(512,2): 2 waves/EU min
// -> 1 block/CU -> 256-VGPR cap, so both rows' 92 weight dwords stay in VGPRs.
// h is broadcast via v_readlane (SALU path) instead of redundant uniform LDS reads:
// each wave holds h as 2 dwords/lane (hf0/hf1), refreshed with 2 ds_read_b32/step.
__global__ __launch_bounds__(512, 2) void k_lstm(const float* __restrict__ zxp,
                                                 const uint32_t* __restrict__ wpack,
                                                 const uint4* __restrict__ wtail,
                                                 const float* __restrict__ h0,
                                                 const float* __restrict__ c0,
                                                 float* __restrict__ hs) {
    extern __shared__ char smem[];
    half_t* h2h = (half_t*)smem;                 // [2][256] halfs (double buffer)
    uint32_t* h2d = (uint32_t*)smem;             // dword view: [2][128]
    uint4* tail = (uint4*)(smem + 1024);         // [NLC][1024] per-old-thread tail weights

    int d = blockIdx.x;
    int t = threadIdx.x;          // 0..511
    int l = t & 63;
    int w = t >> 6;               // 0..7
    int lj = l & 15;
    int j = (w << 4) | lj;        // hidden unit 0..127; second row is j+128

    uint32_t wr1[4 * NVC], wr2[4 * NVC];
#pragma unroll
    for (int kk = 0; kk < 4 * NVC; kk++) {
        wr1[kk] = wpack[(d * 92 + kk) * 1024 + t];
        wr2[kk] = wpack[(d * 92 + kk) * 1024 + t + 512];
    }
    // stage tail weights into LDS (lane-consecutive 16B -> conflict-free)
#pragma unroll
    for (int cb = 0; cb < NLC; cb++) {
        tail[cb * 1024 + t] = wtail[(d * NLC + cb) * 1024 + t];
        tail[cb * 1024 + t + 512] = wtail[(d * NLC + cb) * 1024 + t + 512];
    }

    float c1 = c0[d * HD + j];
    float c2 = c0[d * HD + j + 128];
    if (t < 128) {
        half2_t p = {(half_t)h0[d * HD + 2 * t], (half_t)h0[d * HD + 2 * t + 1]};
        h2d[t] = __builtin_bit_cast(uint32_t, p);
    }
    __syncthreads();
    uint32_t hf0 = h2d[l];        // h dwords 0..63   (lane l -> dword l)
    uint32_t hf1 = h2d[64 + l];   // h dwords 64..127

    const float* zxd = zxp + (long)d * SLEN * G4;
    float* hsd = hs + (long)d * SLEN * HD;

    // software-pipelined zx reads (hides LLC latency)
    int sx0 = d ? (SLEN - 1) : 0;
    float zx1n = zxd[(long)sx0 * G4 + t];
    float zx2n = zxd[(long)sx0 * G4 + t + 512];

    for (int s = 0; s < SLEN; s++) {
        float zx1 = zx1n, zx2 = zx2n;
        if (s + 1 < SLEN) {
            int sxn = d ? (SLEN - 2 - s) : (s + 1);
            zx1n = zxd[(long)sxn * G4 + t];
            zx2n = zxd[(long)sxn * G4 + t + 512];
        }

        float a10 = 0.f, a11 = 0.f, a20 = 0.f, a21 = 0.f;
        // VGPR-resident weight dwords 0..91: broadcast h dword via readlane (SGPR),
        // one broadcast feeds both rows' dot2. Accumulation order identical to the
        // previous kernel (even dwords -> acc0, odd -> acc1, ascending kd).
#pragma unroll
        for (int kd = 0; kd < 4 * NVC; kd++) {
            uint32_t hw = (uint32_t)__builtin_amdgcn_readlane(
                (int)(kd < 64 ? hf0 : hf1), kd & 63);
            if (kd & 1) {
                a11 = dot2(hw, wr1[kd], a11);
                a21 = dot2(hw, wr2[kd], a21);
            } else {
                a10 = dot2(hw, wr1[kd], a10);
                a20 = dot2(hw, wr2[kd], a20);
            }
        }
        // LDS tail: weight dwords 92..127
#pragma unroll
        for (int cb = 0; cb < NLC; cb++) {
            uint4 t1 = tail[cb * 1024 + t];
            uint4 t2 = tail[cb * 1024 + t + 512];
#pragma unroll
            for (int qq = 0; qq < 4; qq++) {
                int kd = 92 + 4 * cb + qq;
                uint32_t hw = (uint32_t)__builtin_amdgcn_readlane((int)hf1, kd - 64);
                uint32_t w1v = (qq == 0) ? t1.x : (qq == 1) ? t1.y : (qq == 2) ? t1.z : t1.w;
                uint32_t w2v = (qq == 0) ? t2.x : (qq == 1) ? t2.y : (qq == 2) ? t2.z : t2.w;
                if (kd & 1) {
                    a11 = dot2(hw, w1v, a11);
                    a21 = dot2(hw, w2v, a21);
                } else {
                    a10 = dot2(hw, w1v, a10);
                    a20 = dot2(hw, w2v, a20);
                }
            }
        }

        float z1 = a10 + a11 + zx1;   // gate row g*256 + j
        float z2 = a20 + a21 + zx2;   // gate row g*256 + j + 128

        float zi1 = __shfl(z1, lj, 64);
        float zf1 = __shfl(z1, lj + 16, 64);
        float zg1 = __shfl(z1, lj + 32, 64);
        float zo1 = __shfl(z1, lj + 48, 64);
        float zi2 = __shfl(z2, lj, 64);
        float zf2 = __shfl(z2, lj + 16, 64);
        float zg2 = __shfl(z2, lj + 32, 64);
        float zo2 = __shfl(z2, lj + 48, 64);

        float ig1 = fsig(zi1), fg1 = fsig(zf1), og1 = fsig(zo1);
        float gg1 = ftanh(zg1);
        c1 = fg1 * c1 + ig1 * gg1;
        float hv1 = og1 * ftanh(c1);

        float ig2 = fsig(zi2), fg2 = fsig(zf2), og2 = fsig(zo2);
        float gg2 = ftanh(zg2);
        c2 = fg2 * c2 + ig2 * gg2;
        float hv2 = og2 * ftanh(c2);

        int nb = (s & 1) ^ 1;   // buffer the NEW h goes into
        if (l < 32) {
            int hid = (l < 16) ? j : (j + 128);
            float hv = (l < 16) ? hv1 : hv2;
            int sx = d ? (SLEN - 1 - s) : s;
            hsd[(long)sx * HD + hid] = hv;
            h2h[nb * 256 + hid] = (half_t)hv;
        }
        __syncthreads();
        hf0 = h2d[nb * 128 + l];
        hf1 = h2d[nb * 128 + 64 + l];
    }
}

// ---------------- feats[s][k] = emitW[k] . [h_fwd[s], h_bwd[s]] + emit_b[k] ----------------
__global__ __launch_bounds__(192) void k_feats(const float* __restrict__ hs,
                                               const float* __restrict__ emitW,
                                               const float* __restrict__ emitb,
                                               float* __restrict__ feats) {
    __shared__ float wb[KT][516];
    __shared__ float hb[8][516];
    int tid = threadIdx.x;
    int s0 = blockIdx.x * 8;
    for (int idx = tid; idx < KT * 512; idx += 192) {
        wb[idx >> 9][idx & 511] = emitW[idx];
    }
    for (int idx = tid; idx < 8 * 512; idx += 192) {
        int sl = idx >> 9, jj = idx & 511;
        float v = (jj < 256) ? hs[(long)(s0 + sl) * HD + jj]
                             : hs[(long)(SLEN + s0 + sl) * HD + (jj - 256)];
        hb[sl][jj] = v;
    }
    __syncthreads();
    if (tid < 160) {
        int sl = tid / KT, k = tid % KT;
        float acc = emitb[k];
        for (int jj = 0; jj < 512; jj += 4) {
            float4 wv = *(const float4*)&wb[k][jj];
            float4 hv = *(const float4*)&hb[sl][jj];
            acc += wv.x * hv.x + wv.y * hv.y + wv.z * hv.z + wv.w * hv.w;
        }
        feats[(long)(s0 + sl) * KT + k] = acc;
    }
}

// ---------------- gold path score -> out[1] ----------------
__global__ __launch_bounds__(256) void k_gold(const float* __restrict__ feats,
                                              const int* __restrict__ tags,
                                              const float* __restrict__ trans,
                                              float* __restrict__ out) {
    __shared__ float red[256];
    int tid = threadIdx.x;
    float local = 0.f;
    for (int s2 = tid; s2 < SLEN; s2 += 256) {
        int cur = tags[s2];
        int prev = s2 ? tags[s2 - 1] : START_ID;
        local += trans[cur * KT + prev] + feats[(long)s2 * KT + cur];
    }
    red[tid] = local;
    __syncthreads();
    for (int off = 128; off; off >>= 1) {
        if (tid < off) red[tid] += red[tid + off];
        __syncthreads();
    }
    if (tid == 0) out[1] = red[0] + trans[STOP_ID * KT + tags[SLEN - 1]];
}

// ---------------- CRF: chunk of 16 step-matrices -> one 20x20 log-space matrix ----------------
__global__ __launch_bounds__(512) void k_crf_chunk(const float* __restrict__ feats,
                                                   const float* __restrict__ trans,
                                                   float* __restrict__ mats) {
    __shared__ float T[KT][KT + 1];
    __shared__ float fb[16][KT];
    __shared__ float cur[2][KT][KT + 1];
    int tid = threadIdx.x;
    int t0 = blockIdx.x * 16;
    if (tid < KT * KT) T[tid / KT][tid % KT] = trans[tid];
    for (int idx = tid; idx < 16 * KT; idx += 512) fb[idx / KT][idx % KT] = feats[(long)t0 * KT + idx];
    __syncthreads();
    int i = tid / KT, jc = tid % KT;
    bool act = tid < KT * KT;
    if (act) cur[0][i][jc] = T[i][jc] + fb[0][i];
    __syncthreads();
    for (int m = 1; m < 16; m++) {
        int p = (m - 1) & 1;
        float nv = 0.f;
        if (act) {
            float vs[KT], vmax = -1e30f;
#pragma unroll
            for (int k = 0; k < KT; k++) { vs[k] = T[i][k] + cur[p][k][jc]; vmax = fmaxf(vmax, vs[k]); }
            float sum = 0.f;
#pragma unroll
            for (int k = 0; k < KT; k++) sum += __expf(vs[k] - vmax);
            nv = fb[m][i] + vmax + __logf(sum);
        }
        if (act) cur[p ^ 1][i][jc] = nv;
        __syncthreads();
    }
    if (act) mats[(long)blockIdx.x * (KT * KT) + tid] = cur[1][i][jc];
}

// ---------------- CRF: combine per_block consecutive matrices (left-applied) ----------------
__global__ __launch_bounds__(512) void k_crf_combine(const float* __restrict__ in,
                                                     float* __restrict__ out_mats,
                                                     int per_block,
                                                     const float* __restrict__ trans,
                                                     float* __restrict__ d_out_ptr,
                                                     int finalize) {
    __shared__ float A[KT][KT + 1];
    __shared__ float cur[2][KT][KT + 1];
    int tid = threadIdx.x;
    int b = blockIdx.x;
    int i = tid / KT, jc = tid % KT;
    bool act = tid < KT * KT;
    const float* base = in + (long)b * per_block * (KT * KT);
    if (act) cur[0][i][jc] = base[tid];
    __syncthreads();
    for (int m = 1; m < per_block; m++) {
        int p = (m - 1) & 1;
        if (act) A[i][jc] = base[(long)m * KT * KT + tid];
        __syncthreads();
        float nv = 0.f;
        if (act) {
            float vs[KT], vmax = -1e30f;
#pragma unroll
            for (int k = 0; k < KT; k++) { vs[k] = A[i][k] + cur[p][k][jc]; vmax = fmaxf(vmax, vs[k]); }
            float sum = 0.f;
#pragma unroll
            for (int k = 0; k < KT; k++) sum += __expf(vs[k] - vmax);
            nv = vmax + __logf(sum);
        }
        if (act) cur[p ^ 1][i][jc] = nv;
        __syncthreads();
    }
    int fbuf = (per_block - 1) & 1;
    if (!finalize) {
        if (act) out_mats[(long)b * KT * KT + tid] = cur[fbuf][i][jc];
        return;
    }
    if (tid == 0) {
        float fv[KT];
        for (int ii = 0; ii < KT; ii++) {
            float vs[KT], vmax = -1e30f;
            for (int k = 0; k < KT; k++) {
                float v = cur[fbuf][ii][k] + (k == START_ID ? 0.f : -10000.f);
                vs[k] = v;
                vmax = fmaxf(vmax, v);
            }
            float sum = 0.f;
            for (int k = 0; k < KT; k++) sum += __expf(vs[k] - vmax);
            fv[ii] = vmax + __logf(sum);
        }
        float vs2[KT], vmax = -1e30f;
        for (int ii = 0; ii < KT; ii++) {
            float v = fv[ii] + trans[STOP_ID * KT + ii];
            vs2[ii] = v;
            vmax = fmaxf(vmax, v);
        }
        float sum = 0.f;
        for (int ii = 0; ii < KT; ii++) sum += __expf(vs2[ii] - vmax);
        d_out_ptr[0] = vmax + __logf(sum);
    }
}

extern "C" void kernel_launch(void* const* d_in, const int* in_sizes, int n_in,
                              void* d_out, int out_size, void* d_ws, size_t ws_size,
                              hipStream_t stream) {
    const int* sentence = (const int*)d_in[0];
    const int* tags = (const int*)d_in[1];
    const float* embed = (const float*)d_in[2];
    const float* w_ih_f = (const float*)d_in[3];
    const float* w_hh_f = (const float*)d_in[4];
    const float* b_f = (const float*)d_in[5];
    const float* w_ih_b = (const float*)d_in[6];
    const float* w_hh_b = (const float*)d_in[7];
    const float* b_b = (const float*)d_in[8];
    const float* h0 = (const float*)d_in[9];
    const float* c0 = (const float*)d_in[10];
    const float* emit_W = (const float*)d_in[11];
    const float* emit_b = (const float*)d_in[12];
    const float* transition = (const float*)d_in[13];
    float* out = (float*)d_out;

    char* ws = (char*)d_ws;
    float* zxp = (float*)(ws + 0);                       // 2*4096*1024 f32 = 32 MB
    float* hs = (float*)(ws + 33554432);                 // 2*4096*256 f32  = 8 MB
    float* wT = (float*)(ws + 41943040);                 // 2*256*1024 f32  = 2 MB
    uint32_t* wpack = (uint32_t*)(ws + 44040192);        // 2*92*1024 u32 = 736 KB
    uint32_t* wtail = (uint32_t*)(ws + 44793856);        // 2*9*1024*4 u32 = 288 KB
    float* feats = (float*)(ws + 45088768);              // 4096*20 f32
    float* mats = (float*)(ws + 45416448);               // 256*400 f32
    float* mats2 = (float*)(ws + 45826048);              // 16*400 f32

    // opt-in to >64KB dynamic LDS for k_lstm (idempotent host call, not a stream op)
    (void)hipFuncSetAttribute((const void*)k_lstm,
                              hipFuncAttributeMaxDynamicSharedMemorySize,
                              LSTM_LDS_BYTES);

    k_transpose_ih<<<dim3(32, 8, 2), 256, 0, stream>>>(w_ih_f, w_ih_b, wT);
    k_pack_hh<<<dim3(101, 2), 1024, 0, stream>>>(w_hh_f, w_hh_b, wpack, wtail);
    k_zx<<<dim3(256, 2), 256, 0, stream>>>(sentence, embed, wT, b_f, b_b, zxp);
    k_lstm<<<dim3(2), 512, LSTM_LDS_BYTES, stream>>>(zxp, wpack, (const uint4*)wtail, h0, c0, hs);
    k_feats<<<dim3(512), 192, 0, stream>>>(hs, emit_W, emit_b, feats);
    k_gold<<<dim3(1), 256, 0, stream>>>(feats, tags, transition, out);
    k_crf_chunk<<<dim3(256), 512, 0, stream>>>(feats, transition, mats);
    k_crf_combine<<<dim3(16), 512, 0, stream>>>(mats, mats2, 16, transition, out, 0);
    k_crf_combine<<<dim3(1), 512, 0, stream>>>(mats2, nullptr, 16, transition, out, 1);
}